// Round 8
// baseline (510.265 us; speedup 1.0000x reference)
//
#include <hip/hip_runtime.h>
#include <math.h>

// SGRUCell T=32 B=8 I=512 H=512, all f32.
// Persistent kernel, 512 blocks x 1024 threads (2 blocks/CU, forced by
// __launch_bounds__(1024,8) => VGPR<=64, all blocks co-resident).
// Block (q=blk>>3, b=blk&7) owns rows i in [8q,8q+8) of batch b; each row is
// split across 2 waves (256 cols each) so every per-row table is float[4]:
// wz,wdv,mw,mb,al,upS,loS,D(=alpha*dU),tE = 36 persistent VGPRs -- fits the
// 64-reg budget with zero spill (rounds 6/7 spilled at [8] arrays: 25 MB
// WRITE_SIZE vs 17.4 ideal). Weight-norm scales computed per block in the
// prologue (no separate prenorm kernel). Cross-block sync = round-6's proven
// flag scheme: producers atomic-store h bits into per-step hx slots, drain
// (s_waitcnt), then store flag = t+1 into the per-(b,q) slot; consumers poll
// the 64 batch flags with one wave, SIGNED >= t (0xAAAAAAAA poison is
// negative => no flag-clearing pass, no ABA). No fences anywhere.

__device__ __forceinline__ float wred(float v) {
#pragma unroll
  for (int o = 32; o > 0; o >>= 1) v += __shfl_xor(v, o, 64);
  return v;
}
__device__ __forceinline__ float sigm(float x) { return 1.f / (1.f + __expf(-x)); }

__global__ __launch_bounds__(1024, 8) void persist_kernel(
    const float* __restrict__ x,
    const float* __restrict__ h0, const float* __restrict__ v0,
    const float* __restrict__ dU0, const float* __restrict__ te0,
    const float* __restrict__ tE0,
    const float* __restrict__ x2h_v, const float* __restrict__ x2h_g,
    const float* __restrict__ x2h_b,
    const float* __restrict__ h2h_v, const float* __restrict__ h2h_g,
    const float* __restrict__ h2h_b,
    const float* __restrict__ alpha,
    const float* __restrict__ h2mod_w, const float* __restrict__ h2mod_b,
    const float* __restrict__ modU_w, const float* __restrict__ modU_b,
    unsigned* __restrict__ hx, int* __restrict__ flg,
    float* __restrict__ o_v, float* __restrict__ o_h,
    float* __restrict__ o_dU, float* __restrict__ o_te,
    float* __restrict__ o_tE, float* __restrict__ o_outs) {
  __shared__ float sh_h[2][512];      // h ping-pong: sh_h[t&1] = h_t
  __shared__ float sh_te[512];        // eligibility trace for this batch
  __shared__ float sh_mod[2048];      // h2mod_w (4x512)
  __shared__ float sh_xpz[32][8];     // x-proj (z) + biases, [t][local row]
  __shared__ float sh_xpdv[32][8];    // x-proj (dv) + biases
  __shared__ float sh_xtmp[32][16][2];// per-wave x-proj partials
  __shared__ float sh_part[16][2];    // per-wave dot partials (p1,p2)
  __shared__ float sh_sc[8][5];       // per-row norm scales: hz,hr,hdv,xz,xdv
  __shared__ float sh_gates[4];       // tau_e, tau_E, tau_U, mU

  const int tid = threadIdx.x;
  const int w = tid >> 6, L = tid & 63;
  const int b = blockIdx.x & 7, q = blockIdx.x >> 3;   // q in [0,64)
  const int r = w >> 1;              // local row 0..7
  const int hh = w & 1;              // row half 0/1
  const int i = q * 8 + r;           // global row
  const int cb = hh * 256;           // column base for this wave

  // ---- LDS staging ----
  if (tid < 512) {
    sh_h[0][tid] = h0[b * 512 + tid];
    sh_te[tid] = te0[b * 512 + tid];
  }
  sh_mod[tid] = h2mod_w[tid];
  sh_mod[tid + 1024] = h2mod_w[tid + 1024];

  // ---- per-block weight-norm scales (prenorm kernel folded in) ----
  {
    if (hh == 0) {  // h2h rows i, 512+i, 1024+i
      const float* p0 = h2h_v + (size_t)i * 512;
      const float* p1 = h2h_v + (size_t)(512 + i) * 512;
      const float* p2 = h2h_v + (size_t)(1024 + i) * 512;
      float s0 = 0.f, s1 = 0.f, s2 = 0.f;
#pragma unroll
      for (int m = 0; m < 8; m++) {
        int c = m * 64 + L;
        float a0 = p0[c], a1 = p1[c], a2 = p2[c];
        s0 = fmaf(a0, a0, s0); s1 = fmaf(a1, a1, s1); s2 = fmaf(a2, a2, s2);
      }
      s0 = wred(s0); s1 = wred(s1); s2 = wred(s2);
      if (L == 0) {
        sh_sc[r][0] = h2h_g[i] / sqrtf(s0);
        sh_sc[r][1] = h2h_g[512 + i] / sqrtf(s1);
        sh_sc[r][2] = h2h_g[1024 + i] / sqrtf(s2);
      }
    } else {        // x2h rows i, 1024+i
      const float* p0 = x2h_v + (size_t)i * 512;
      const float* p1 = x2h_v + (size_t)(1024 + i) * 512;
      float s0 = 0.f, s1 = 0.f;
#pragma unroll
      for (int m = 0; m < 8; m++) {
        int c = m * 64 + L;
        float a0 = p0[c], a1 = p1[c];
        s0 = fmaf(a0, a0, s0); s1 = fmaf(a1, a1, s1);
      }
      s0 = wred(s0); s1 = wred(s1);
      if (L == 0) {
        sh_sc[r][3] = x2h_g[i] / sqrtf(s0);
        sh_sc[r][4] = x2h_g[1024 + i] / sqrtf(s1);
      }
    }
  }
  __syncthreads();

  const size_t row  = ((size_t)(b * 512 + i)) * 512;
  const size_t wrow = (size_t)i * 512;
  const float s_z = sh_sc[r][0], s_r = sh_sc[r][1], s_dv = sh_sc[r][2];
  const float sx_z = sh_sc[r][3], sx_dv = sh_sc[r][4];

  // ---- x-projection precompute (h-independent, all 32 steps) ----
  {
    float xz[4], xdv[4];
#pragma unroll
    for (int m = 0; m < 4; m++) {
      int c = cb + m * 64 + L;
      xz[m]  = sx_z  * x2h_v[(size_t)i * 512 + c];
      xdv[m] = sx_dv * x2h_v[(size_t)(1024 + i) * 512 + c];
    }
#pragma unroll 4
    for (int t = 0; t < 32; t++) {
      const float* xr = x + (size_t)t * 4096 + b * 512;
      float a = 0.f, d = 0.f;
#pragma unroll
      for (int m = 0; m < 4; m++) {
        int c = cb + m * 64 + L;
        float xv_ = xr[c];
        a = fmaf(xz[m], xv_, a);
        d = fmaf(xdv[m], xv_, d);
      }
      a = wred(a); d = wred(d);
      if (L == 0) { sh_xtmp[t][w][0] = a; sh_xtmp[t][w][1] = d; }
    }
  }
  __syncthreads();
  if (tid < 256) {  // combine halves + add biases
    int tt = tid >> 3, r2 = tid & 7, i2 = q * 8 + r2;
    sh_xpz[tt][r2]  = sh_xtmp[tt][2 * r2][0] + sh_xtmp[tt][2 * r2 + 1][0]
                      + x2h_b[i2] + h2h_b[i2];
    sh_xpdv[tt][r2] = sh_xtmp[tt][2 * r2][1] + sh_xtmp[tt][2 * r2 + 1][1]
                      + x2h_b[1024 + i2] + h2h_b[1024 + i2];
  }

  // ---- persistent register tables (float[4] each -- no spill at 64 VGPR) ----
  float wz[4], wdv[4], mw[4], mb[4], al[4], upS[4], loS[4], D[4], tE[4];
#pragma unroll
  for (int m = 0; m < 4; m++) {
    int c = cb + m * 64 + L;
    wz[m]  = s_z  * h2h_v[(size_t)i * 512 + c];
    wdv[m] = s_dv * h2h_v[(size_t)(1024 + i) * 512 + c];
    mw[m] = modU_w[wrow + c];
    mb[m] = modU_b[wrow + c];
    float alv = alpha[wrow + c];
    al[m] = alv;
    float wrv = s_r * h2h_v[(size_t)(512 + i) * 512 + c];
    float t1 = alv / (alv + 1e-5f);     // alpha-prescaled clip factor
    upS[m] = fmaxf(1.f - wrv, 0.f) * t1;
    loS[m] = -fmaxf(1.f + wrv, 0.f) * t1;
    D[m]  = alv * dU0[row + c];         // scaled state: D = alpha*dU
    tE[m] = tE0[row + c];
  }
  float v_reg = 0.f, hn_last = 0.f, gb = 0.f;
  if (L == 0) {
    if (hh == 0) v_reg = v0[b * 512 + i];
    if (w < 4) gb = h2mod_b[w];
  }
  __syncthreads();

  for (int t = 0; t <= 32; t++) {
    const int cur = t & 1, prev = cur ^ 1;
    if (t > 0) {
      // ---- sync in: one wave polls the 64 batch flags (signed >= t) ----
      if (w == 0) {
        const int* fp = flg + b * 64 + L;
        int u = __hip_atomic_load(fp, __ATOMIC_RELAXED, __HIP_MEMORY_SCOPE_AGENT);
        while (!__all(u >= t)) {
          u = __hip_atomic_load(fp, __ATOMIC_RELAXED, __HIP_MEMORY_SCOPE_AGENT);
        }
      }
      __syncthreads();
      if (tid < 512) {  // one-shot read of h_t
        unsigned u = __hip_atomic_load(hx + (size_t)(t - 1) * 4096 + b * 512 + tid,
                                       __ATOMIC_RELAXED, __HIP_MEMORY_SCOPE_AGENT);
        sh_h[cur][tid] = __uint_as_float(u);
      }
      __syncthreads();
      // gates: mod = h_t @ h2mod_w.T + b, waves 0..3 (full 512 each)
      if (w < 4) {
        float p = 0.f;
        const float* mr = sh_mod + w * 512;
#pragma unroll
        for (int m = 0; m < 8; m++) {
          int c = m * 64 + L;
          p = fmaf(sh_h[cur][c], mr[c], p);
        }
        p = wred(p);
        if (L == 0) {
          p += gb;
          sh_gates[w] = (w == 3) ? fmaxf(p, 0.f) : sigm(p);
        }
      }
      __syncthreads();
      // te_n = te + tau_e*(h_{t-1} - te)
      float taue = sh_gates[0];
      if (tid < 512) sh_te[tid] += taue * (sh_h[prev][tid] - sh_te[tid]);
      __syncthreads();
      // tE / D register update (pure VALU, no memory)
      float tauE = sh_gates[1], tauU = sh_gates[2], mU = sh_gates[3];
      float hn_i = sh_h[cur][i], te_i = sh_te[i];
#pragma unroll
      for (int m = 0; m < 4; m++) {
        int j = cb + m * 64 + L;
        float outer = hn_i * sh_te[j] - te_i * sh_h[cur][j];
        float tEn = tE[m] + tauE * (outer - tE[m]);
        float a = fmaf(mU, mw[m], mb[m]);
        float sshr = (a > 0.5f) ? (a - 0.5f) : ((a < -0.5f) ? (a + 0.5f) : 0.f);
        float Dn = D[m] + tauU * (sshr * (al[m] * tEn) - D[m]);
        D[m] = fminf(fmaxf(Dn, loS[m]), upS[m]);
        tE[m] = tEn;
      }
    }

    if (t < 32) {
      // z/dv half-row dots for step t
      float p1 = 0.f, p2 = 0.f;
#pragma unroll
      for (int m = 0; m < 4; m++) {
        int c = cb + m * 64 + L;
        float hc = sh_h[cur][c];
        p1 = fmaf(wz[m], hc, p1);
        p2 = fmaf(wdv[m] + D[m], hc, p2);
      }
      p1 = wred(p1); p2 = wred(p2);
      if (L == 0) { sh_part[w][0] = p1; sh_part[w][1] = p2; }
      __syncthreads();
      if (hh == 0 && L == 0) {  // combine halves, advance v/h, publish
        float f1 = sh_part[w][0] + sh_part[w + 1][0];
        float f2 = sh_part[w][1] + sh_part[w + 1][1];
        float z = sigm(f1 + sh_xpz[t][r]);
        float dv = f2 + sh_xpdv[t][r];
        v_reg += z * (dv - v_reg);
        hn_last = fmaxf(v_reg, 0.f);
        o_outs[(size_t)t * 4096 + b * 512 + i] = hn_last;
        __hip_atomic_store(hx + (size_t)t * 4096 + b * 512 + i,
                           __float_as_uint(hn_last),
                           __ATOMIC_RELAXED, __HIP_MEMORY_SCOPE_AGENT);
      }
      __builtin_amdgcn_s_waitcnt(0);  // drain h stores (per-wave) before flag
      __syncthreads();
      if (tid == 0)
        __hip_atomic_store(flg + b * 64 + q, t + 1,
                           __ATOMIC_RELAXED, __HIP_MEMORY_SCOPE_AGENT);
    }
  }

  // ---- final writes ----
#pragma unroll
  for (int m = 0; m < 4; m++) {
    int c = cb + m * 64 + L;
    float alv = al[m];
    o_dU[row + c] = (alv != 0.f) ? D[m] * __builtin_amdgcn_rcpf(alv) : 0.f;
    o_tE[row + c] = tE[m];
  }
  if (hh == 0 && L == 0) {
    o_v[b * 512 + i] = v_reg;
    o_h[b * 512 + i] = hn_last;
  }
  if (q == 0 && tid < 512) o_te[b * 512 + tid] = sh_te[tid];
}

extern "C" void kernel_launch(void* const* d_in, const int* in_sizes, int n_in,
                              void* d_out, int out_size, void* d_ws, size_t ws_size,
                              hipStream_t stream) {
  const float* x       = (const float*)d_in[0];
  const float* h0      = (const float*)d_in[1];
  const float* v0      = (const float*)d_in[2];
  const float* dU0     = (const float*)d_in[3];
  const float* te0     = (const float*)d_in[4];
  const float* tE0     = (const float*)d_in[5];
  const float* x2h_v   = (const float*)d_in[6];
  const float* x2h_g   = (const float*)d_in[7];
  const float* x2h_b   = (const float*)d_in[8];
  const float* h2h_v   = (const float*)d_in[9];
  const float* h2h_g   = (const float*)d_in[10];
  const float* h2h_b   = (const float*)d_in[11];
  const float* alpha   = (const float*)d_in[12];
  const float* h2mod_w = (const float*)d_in[13];
  const float* h2mod_b = (const float*)d_in[14];
  const float* modU_w  = (const float*)d_in[15];
  const float* modU_b  = (const float*)d_in[16];

  float* out = (float*)d_out;
  // output layout: v(4096) h(4096) dU(2097152) te(4096) tE(2097152) outs(131072)
  float* o_v    = out;
  float* o_h    = out + 4096;
  float* o_dU   = out + 8192;
  float* o_te   = out + 2105344;
  float* o_tE   = out + 2109440;
  float* o_outs = out + 4206592;

  unsigned* hx = (unsigned*)d_ws;   // 32*4096 per-step h-exchange slots (512 KB)
  int* flg = (int*)(hx + 131072);   // 8 batches x 64 block-flags (2 KB);
                                    // 0xAA poison is negative => no clearing

  persist_kernel<<<dim3(512), dim3(1024), 0, stream>>>(
      x, h0, v0, dU0, te0, tE0, x2h_v, x2h_g, x2h_b, h2h_v, h2h_g, h2h_b,
      alpha, h2mod_w, h2mod_b, modU_w, modU_b, hx, flg,
      o_v, o_h, o_dU, o_te, o_tE, o_outs);
}

// Round 9
// 282.839 us; speedup vs baseline: 1.8041x; 1.8041x over previous
//
#include <hip/hip_runtime.h>
#include <math.h>

// SGRUCell T=32 B=8 I=512 H=512, all f32.
// Single persistent kernel, 256 blocks x 1024 threads (1 block/CU).
// Block (q=blk>>3, b=blk&7) owns rows i in [16q,16q+16) of batch b; 16 waves,
// one full row per wave. Per-row tables wz,wdv,mw,mb,al,upS,loS + state
// D(=alpha*dU),tE in registers (72 persistent VGPRs).
//
// KEY FIX vs rounds 5-8: __launch_bounds__ arg2 has CUDA semantics (min
// BLOCKS/CU) on this toolchain -- (1024,4) capped VGPR at 64 and forced the
// spills we chased for three rounds ((1024,8) capped at 32: 79 MB scratch
// writes + 41 ms near-deadlock). (1024,1) releases the cap to 128 (the max
// schedulable for a 16-wave block), so the tables fit with zero spill.
//
// Weight-norm scales are wave-local (wred leaves the sum in all 64 lanes ->
// no LDS, no sync) so the prenorm kernel is gone: ONE dispatch.
// Cross-block sync (round-6 proven): producers atomic-store h bits into
// o_outs (relaxed agent), s_waitcnt, then tid0 stores flag = t+1 into the
// per-(b,q) slot; consumers poll the 32 batch flags with one wave, signed
// >= t (0xAAAAAAAA poison is negative => no clearing, monotonic => no ABA).

__device__ __forceinline__ float wred(float v) {
#pragma unroll
  for (int o = 32; o > 0; o >>= 1) v += __shfl_xor(v, o, 64);
  return v;
}
__device__ __forceinline__ float sigm(float x) { return 1.f / (1.f + __expf(-x)); }

__global__ __launch_bounds__(1024, 1) void persist_kernel(
    const float* __restrict__ x,
    const float* __restrict__ h0, const float* __restrict__ v0,
    const float* __restrict__ dU0, const float* __restrict__ te0,
    const float* __restrict__ tE0,
    const float* __restrict__ x2h_v, const float* __restrict__ x2h_g,
    const float* __restrict__ x2h_b,
    const float* __restrict__ h2h_v, const float* __restrict__ h2h_g,
    const float* __restrict__ h2h_b,
    const float* __restrict__ alpha,
    const float* __restrict__ h2mod_w, const float* __restrict__ h2mod_b,
    const float* __restrict__ modU_w, const float* __restrict__ modU_b,
    int* __restrict__ flg,
    float* __restrict__ o_v, float* __restrict__ o_h,
    float* __restrict__ o_dU, float* __restrict__ o_te,
    float* __restrict__ o_tE, float* __restrict__ o_outs) {
  __shared__ float sh_h[2][512];      // h ping-pong: sh_h[t&1] = h_t
  __shared__ float sh_te[512];        // eligibility trace for this batch
  __shared__ float sh_mod[2048];      // h2mod_w (4x512)
  __shared__ float sh_xpz[32][16];    // x-proj (z) + biases, [t][wave/row]
  __shared__ float sh_xpdv[32][16];   // x-proj (dv) + biases
  __shared__ float sh_gates[4];       // tau_e, tau_E, tau_U, mU

  const int tid = threadIdx.x;
  const int w = tid >> 6, L = tid & 63;
  const int b = blockIdx.x & 7, q = blockIdx.x >> 3;  // q in [0,32)
  const int i = q * 16 + w;  // owned row

  // ---- LDS staging ----
  if (tid < 512) {
    sh_h[0][tid] = h0[b * 512 + tid];
    sh_te[tid] = te0[b * 512 + tid];
  }
  sh_mod[tid] = h2mod_w[tid];
  sh_mod[tid + 1024] = h2mod_w[tid + 1024];

  const size_t row  = ((size_t)(b * 512 + i)) * 512;
  const size_t wrow = (size_t)i * 512;
  const float* hz_row  = h2h_v + (size_t)i * 512;
  const float* hr_row  = h2h_v + (size_t)(512 + i) * 512;
  const float* hdv_row = h2h_v + (size_t)(1024 + i) * 512;
  const float* xz_row  = x2h_v + (size_t)i * 512;
  const float* xdv_row = x2h_v + (size_t)(1024 + i) * 512;

  // ---- weight-norm scales: pure wave-local (wred gives sum to ALL lanes) ----
  float s_z, s_r, s_dv, sx_z, sx_dv;
  {
    float n0 = 0.f, n1 = 0.f, n2 = 0.f, n3 = 0.f, n4 = 0.f;
#pragma unroll
    for (int m = 0; m < 8; m++) {
      int c = m * 64 + L;
      float a0 = hz_row[c], a1 = hr_row[c], a2 = hdv_row[c];
      float a3 = xz_row[c], a4 = xdv_row[c];
      n0 = fmaf(a0, a0, n0); n1 = fmaf(a1, a1, n1); n2 = fmaf(a2, a2, n2);
      n3 = fmaf(a3, a3, n3); n4 = fmaf(a4, a4, n4);
    }
    n0 = wred(n0); n1 = wred(n1); n2 = wred(n2); n3 = wred(n3); n4 = wred(n4);
    s_z  = h2h_g[i] / sqrtf(n0);
    s_r  = h2h_g[512 + i] / sqrtf(n1);
    s_dv = h2h_g[1024 + i] / sqrtf(n2);
    sx_z  = x2h_g[i] / sqrtf(n3);
    sx_dv = x2h_g[1024 + i] / sqrtf(n4);
  }

  // ---- x-projection precompute (h-independent, all 32 steps) ----
  {
    float xz[8], xdv[8];
#pragma unroll
    for (int m = 0; m < 8; m++) {
      int c = m * 64 + L;
      xz[m]  = sx_z  * xz_row[c];
      xdv[m] = sx_dv * xdv_row[c];
    }
    float bz = 0.f, bdv = 0.f;
    if (L == 0) {
      bz  = x2h_b[i] + h2h_b[i];
      bdv = x2h_b[1024 + i] + h2h_b[1024 + i];
    }
#pragma unroll 4
    for (int t = 0; t < 32; t++) {
      const float* xr = x + (size_t)t * 4096 + b * 512;
      float a = 0.f, d = 0.f;
#pragma unroll
      for (int m = 0; m < 8; m++) {
        int c = m * 64 + L;
        float xv_ = xr[c];
        a = fmaf(xz[m], xv_, a);
        d = fmaf(xdv[m], xv_, d);
      }
      a = wred(a); d = wred(d);
      if (L == 0) { sh_xpz[t][w] = a + bz; sh_xpdv[t][w] = d + bdv; }
    }
  }

  // ---- persistent register tables (fit in 128-VGPR budget, no spill) ----
  float wz[8], wdv[8], mw[8], mb[8], al[8], upS[8], loS[8], D[8], tE[8];
#pragma unroll
  for (int m = 0; m < 8; m++) {
    int c = m * 64 + L;
    wz[m]  = s_z  * hz_row[c];
    wdv[m] = s_dv * hdv_row[c];
    mw[m] = modU_w[wrow + c];
    mb[m] = modU_b[wrow + c];
    float alv = alpha[wrow + c];
    al[m] = alv;
    float wrv = s_r * hr_row[c];
    float t1 = alv / (alv + 1e-5f);     // alpha-prescaled clip factor
    upS[m] = fmaxf(1.f - wrv, 0.f) * t1;
    loS[m] = -fmaxf(1.f + wrv, 0.f) * t1;
    D[m]  = alv * dU0[row + c];         // scaled state: D = alpha*dU
    tE[m] = tE0[row + c];
  }
  float v_reg = 0.f, hn_last = 0.f, gb = 0.f;
  if (L == 0) {
    v_reg = v0[b * 512 + i];
    if (w < 4) gb = h2mod_b[w];
  }
  __syncthreads();

  unsigned* hxu = (unsigned*)o_outs;  // h exchanged through the output buffer

  for (int t = 0; t <= 32; t++) {
    const int cur = t & 1, prev = cur ^ 1;
    if (t > 0) {
      // ---- sync in: one wave polls the 32 batch flags (signed >= t) ----
      if (w == 0) {
        const int* fp = flg + b * 32 + (L & 31);
        int u = __hip_atomic_load(fp, __ATOMIC_RELAXED, __HIP_MEMORY_SCOPE_AGENT);
        while (!__all(u >= t)) {
          u = __hip_atomic_load(fp, __ATOMIC_RELAXED, __HIP_MEMORY_SCOPE_AGENT);
        }
      }
      __syncthreads();
      if (tid < 512) {  // one-shot read of h_t
        unsigned u = __hip_atomic_load(hxu + (size_t)(t - 1) * 4096 + b * 512 + tid,
                                       __ATOMIC_RELAXED, __HIP_MEMORY_SCOPE_AGENT);
        sh_h[cur][tid] = __uint_as_float(u);
      }
      __syncthreads();
      // gates: mod = h_t @ h2mod_w.T + b, waves 0..3
      if (w < 4) {
        float p = 0.f;
        const float* mr = sh_mod + w * 512;
#pragma unroll
        for (int m = 0; m < 8; m++) {
          int c = m * 64 + L;
          p = fmaf(sh_h[cur][c], mr[c], p);
        }
        p = wred(p);
        if (L == 0) {
          p += gb;
          sh_gates[w] = (w == 3) ? fmaxf(p, 0.f) : sigm(p);
        }
      }
      __syncthreads();
      // te_n = te + tau_e*(h_{t-1} - te)
      float taue = sh_gates[0];
      if (tid < 512) sh_te[tid] += taue * (sh_h[prev][tid] - sh_te[tid]);
      __syncthreads();
      // tE / D register update (pure VALU, zero memory traffic)
      float tauE = sh_gates[1], tauU = sh_gates[2], mU = sh_gates[3];
      float hn_i = sh_h[cur][i], te_i = sh_te[i];
#pragma unroll
      for (int m = 0; m < 8; m++) {
        int j = m * 64 + L;
        float outer = hn_i * sh_te[j] - te_i * sh_h[cur][j];
        float tEn = tE[m] + tauE * (outer - tE[m]);
        float a = fmaf(mU, mw[m], mb[m]);
        float sshr = (a > 0.5f) ? (a - 0.5f) : ((a < -0.5f) ? (a + 0.5f) : 0.f);
        float Dn = D[m] + tauU * (sshr * (al[m] * tEn) - D[m]);
        D[m] = fminf(fmaxf(Dn, loS[m]), upS[m]);
        tE[m] = tEn;
      }
    }

    if (t < 32) {
      // z/dv row dots for step t (x-part precomputed; D = alpha*dU)
      float p1 = 0.f, p2 = 0.f;
#pragma unroll
      for (int m = 0; m < 8; m++) {
        int c = m * 64 + L;
        float hc = sh_h[cur][c];
        p1 = fmaf(wz[m], hc, p1);
        p2 = fmaf(wdv[m] + D[m], hc, p2);
      }
      p1 = wred(p1); p2 = wred(p2);
      if (L == 0) {
        float z = sigm(p1 + sh_xpz[t][w]);
        float dv = p2 + sh_xpdv[t][w];
        v_reg += z * (dv - v_reg);
        hn_last = fmaxf(v_reg, 0.f);
        __hip_atomic_store(hxu + (size_t)t * 4096 + b * 512 + i,
                           __float_as_uint(hn_last),
                           __ATOMIC_RELAXED, __HIP_MEMORY_SCOPE_AGENT);
      }
      __builtin_amdgcn_s_waitcnt(0);  // drain h store (per-wave) before flag
      __syncthreads();
      if (tid == 0)
        __hip_atomic_store(flg + b * 32 + q, t + 1,
                           __ATOMIC_RELAXED, __HIP_MEMORY_SCOPE_AGENT);
    }
  }

  // ---- final writes ----
#pragma unroll
  for (int m = 0; m < 8; m++) {
    int c = m * 64 + L;
    float alv = al[m];
    o_dU[row + c] = (alv != 0.f) ? D[m] * __builtin_amdgcn_rcpf(alv) : 0.f;
    o_tE[row + c] = tE[m];
  }
  if (L == 0) {
    o_v[b * 512 + i] = v_reg;
    o_h[b * 512 + i] = hn_last;
  }
  if (q == 0 && tid < 512) o_te[b * 512 + tid] = sh_te[tid];
}

extern "C" void kernel_launch(void* const* d_in, const int* in_sizes, int n_in,
                              void* d_out, int out_size, void* d_ws, size_t ws_size,
                              hipStream_t stream) {
  const float* x       = (const float*)d_in[0];
  const float* h0      = (const float*)d_in[1];
  const float* v0      = (const float*)d_in[2];
  const float* dU0     = (const float*)d_in[3];
  const float* te0     = (const float*)d_in[4];
  const float* tE0     = (const float*)d_in[5];
  const float* x2h_v   = (const float*)d_in[6];
  const float* x2h_g   = (const float*)d_in[7];
  const float* x2h_b   = (const float*)d_in[8];
  const float* h2h_v   = (const float*)d_in[9];
  const float* h2h_g   = (const float*)d_in[10];
  const float* h2h_b   = (const float*)d_in[11];
  const float* alpha   = (const float*)d_in[12];
  const float* h2mod_w = (const float*)d_in[13];
  const float* h2mod_b = (const float*)d_in[14];
  const float* modU_w  = (const float*)d_in[15];
  const float* modU_b  = (const float*)d_in[16];

  float* out = (float*)d_out;
  // output layout: v(4096) h(4096) dU(2097152) te(4096) tE(2097152) outs(131072)
  float* o_v    = out;
  float* o_h    = out + 4096;
  float* o_dU   = out + 8192;
  float* o_te   = out + 2105344;
  float* o_tE   = out + 2109440;
  float* o_outs = out + 4206592;

  int* flg = (int*)d_ws;  // 8 batches x 32 block-flags (1 KB); 0xAA poison is
                          // negative, flags are monotonic t+1 => no clearing

  persist_kernel<<<dim3(256), dim3(1024), 0, stream>>>(
      x, h0, v0, dU0, te0, tE0, x2h_v, x2h_g, x2h_b, h2h_v, h2h_g, h2h_b,
      alpha, h2mod_w, h2mod_b, modU_w, modU_b, flg,
      o_v, o_h, o_dU, o_te, o_tE, o_outs);
}